// Round 15
// baseline (486.814 us; speedup 1.0000x reference)
//
#include <hip/hip_runtime.h>
#include <hip/hip_bf16.h>
#include <cmath>

namespace {
constexpr int Bn = 16, Ln = 4096, Dn = 128, DSn = 16;
constexpr int Mtok = Bn * Ln; // 65536 tokens
constexpr int SLS = 138;      // LDS row stride (ushorts) for 128-col bf16 tiles
}

typedef short bfx8 __attribute__((ext_vector_type(8)));
typedef float f32x4 __attribute__((ext_vector_type(4)));

// hardware bf16 convert (RNE)
static __device__ __forceinline__ ushort f2bf(float f) {
  union { __hip_bfloat16 h; ushort u; } c;
  c.h = __float2bfloat16(f);
  return c.u;
}
static __device__ __forceinline__ float bf2f(ushort u) {
  union { unsigned u; float f; } v; v.u = ((unsigned)u) << 16;
  return v.f;
}
// tanh-form gelu with native exp
static __device__ __forceinline__ float gelu_fast(float x) {
  float u = x * (1.5957691216f + 0.07135481f * x * x);
  return x / (1.f + __expf(-u));
}

// ---------------- all weight preprocessing in one kernel ----------------
__global__ void k_prep(const float* __restrict__ inw, const float* __restrict__ outw,
                       const float* __restrict__ m1, const float* __restrict__ m2,
                       const float* __restrict__ xw, const float* __restrict__ cw,
                       const float* __restrict__ d1, const float* __restrict__ d2,
                       const float* __restrict__ bo, const float* __restrict__ u1,
                       const float* __restrict__ u2, ushort* __restrict__ W3,
                       float* __restrict__ CWT) {
  int i = blockIdx.x * 256 + threadIdx.x;
  if (i < 65536) { W3[i] = f2bf(inw[i]); return; }
  if (i < 98304) { W3[i] = f2bf(outw[i - 65536]); return; }
  if (i < 163840) { W3[i] = f2bf(m1[i - 98304]); return; }
  if (i < 229376) { W3[i] = f2bf(m2[i - 163840]); return; }
  if (i < 233472) { W3[i] = f2bf(xw[i - 229376]); return; }
  if (i < 234496) {
    int j = i - 233472; int blk = j >> 9, r = j & 511, d = r >> 2, k = r & 3;
    CWT[blk * 512 + k * 128 + d] = cw[j]; return;
  }
  if (i < 381952) { // down1: w[co][ci][9], 128->128
    int j = i - 234496; int co = j / (128 * 9); int r = j - co * (128 * 9);
    int ci = r / 9, tap = r - ci * 9;
    W3[233472 + ((size_t)tap * 128 + co) * 128 + ci] = f2bf(d1[j]); return;
  }
  if (i < 676864) { // down2: 128->256
    int j = i - 381952; int co = j / (128 * 9); int r = j - co * (128 * 9);
    int ci = r / 9, tap = r - ci * 9;
    W3[380928 + ((size_t)tap * 256 + co) * 128 + ci] = f2bf(d2[j]); return;
  }
  if (i < 1266688) { // bott: 256->256
    int j = i - 676864; int co = j / (256 * 9); int r = j - co * (256 * 9);
    int ci = r / 9, tap = r - ci * 9;
    W3[675840 + ((size_t)tap * 256 + co) * 256 + ci] = f2bf(bo[j]); return;
  }
  if (i < 1790976) { // up1: w[ci][co][16], 256->128
    int j = i - 1266688; int ci = j / (128 * 16); int r = j - ci * (128 * 16);
    int co = r >> 4, tap = r & 15;
    W3[1265664 + ((size_t)tap * 128 + co) * 256 + ci] = f2bf(u1[j]); return;
  }
  if (i < 2315264) { // up2
    int j = i - 1790976; int ci = j / (128 * 16); int r = j - ci * (128 * 16);
    int co = r >> 4, tap = r & 15;
    W3[1789952 + ((size_t)tap * 128 + co) * 256 + ci] = f2bf(u2[j]); return;
  }
}

// ---------------- embedding ----------------
__global__ void k_combine(const float* __restrict__ x, float* __restrict__ xc) {
  int i = blockIdx.x * 256 + threadIdx.x; // B*HW = 65536
  int b = i >> 12, p = i & 4095;
  const float* xb = x + (size_t)b * 5 * Ln + p;
  xc[i] = 0.5f * (xb[0] + xb[Ln] + xb[2 * Ln] + xb[3 * Ln]) + xb[4 * Ln];
}

// embed + ln1 fused: writes EMB (bf16 residual stream) and XN1 = ln1(EMB) bf16
__global__ __launch_bounds__(256) void k_embedln(
    const float* __restrict__ xc, const float* __restrict__ ew, const float* __restrict__ eb,
    const float* __restrict__ pos, const float* __restrict__ te,
    const float* __restrict__ lw, const float* __restrict__ lb,
    ushort* __restrict__ emb, ushort* __restrict__ xn) {
  int tok = blockIdx.x * 8 + (threadIdx.x >> 5);
  int ln = threadIdx.x & 31;
  int b = tok >> 12, l = tok & 4095;
  int h = l >> 6, w = l & 63;
  const float* xb = xc + b * 4096;
  float v[9];
#pragma unroll
  for (int dy = 0; dy < 3; dy++)
#pragma unroll
    for (int dx = 0; dx < 3; dx++) {
      int y = h + dy - 1, xx = w + dx - 1;
      v[dy * 3 + dx] = (y >= 0 && y < 64 && xx >= 0 && xx < 64) ? xb[y * 64 + xx] : 0.f;
    }
  int d0 = ln * 4;
  float o[4]; float s = 0.f, sq = 0.f;
#pragma unroll
  for (int e = 0; e < 4; e++) {
    int d = d0 + e;
    float a = 0.f;
#pragma unroll
    for (int k = 0; k < 9; k++) a += v[k] * ew[d * 9 + k];
    float ts = 0.5f * (te[d] + te[128 + d] + te[256 + d] + te[384 + d]) + te[512 + d];
    float r = a + 3.f * eb[d] + 3.f * pos[l * 128 + d] + ts;
    o[e] = r; s += r; sq += r * r;
  }
  ushort4 eo;
  eo.x = f2bf(o[0]); eo.y = f2bf(o[1]); eo.z = f2bf(o[2]); eo.w = f2bf(o[3]);
  *(ushort4*)(emb + (size_t)tok * 128 + d0) = eo;
#pragma unroll
  for (int off = 16; off; off >>= 1) { s += __shfl_xor(s, off); sq += __shfl_xor(sq, off); }
  float m = s * (1.f / 128.f);
  float var = sq * (1.f / 128.f) - m * m;
  float rs = rsqrtf(var + 1e-5f);
  ushort4 u;
  u.x = f2bf((o[0] - m) * rs * lw[d0 + 0] + lb[d0 + 0]);
  u.y = f2bf((o[1] - m) * rs * lw[d0 + 1] + lb[d0 + 1]);
  u.z = f2bf((o[2] - m) * rs * lw[d0 + 2] + lb[d0 + 2]);
  u.w = f2bf((o[3] - m) * rs * lw[d0 + 3] + lb[d0 + 3]);
  *(ushort4*)(xn + (size_t)tok * 128 + d0) = u;
}

// ---------------- fused dwconv + residual + sln (bf16 residual) ----------------
__global__ __launch_bounds__(256) void k_fuse1(
    const ushort* __restrict__ xn1, ushort* __restrict__ emb, ushort* __restrict__ xn2,
    const float* __restrict__ cwT, const float* __restrict__ cb,
    const float* __restrict__ sw, const float* __restrict__ sb) {
  int i = blockIdx.x * 256 + threadIdx.x; // Mtok*16
  int g = i & 15, tok = i >> 4, d0 = g * 8, l = tok & 4095;
  const ushort* p = xn1 + (size_t)tok * 128 + d0;
  const bfx8 zf = {0, 0, 0, 0, 0, 0, 0, 0};
  bfx8 v0 = *(const bfx8*)p;
  bfx8 v1 = (l >= 1) ? *(const bfx8*)(p - 128) : zf;
  bfx8 v2 = (l >= 2) ? *(const bfx8*)(p - 256) : zf;
  bfx8 v3 = (l >= 3) ? *(const bfx8*)(p - 384) : zf;
  ushort* ep = emb + (size_t)tok * 128 + d0;
  bfx8 e8 = *(const bfx8*)ep;
  float nv[8]; float s = 0.f, sq = 0.f;
#pragma unroll
  for (int e = 0; e < 8; e++) {
    int d = d0 + e;
    float c = cb[d] + cwT[3 * 128 + d] * bf2f((ushort)v0[e]) + cwT[2 * 128 + d] * bf2f((ushort)v1[e]) +
              cwT[1 * 128 + d] * bf2f((ushort)v2[e]) + cwT[0 * 128 + d] * bf2f((ushort)v3[e]);
    nv[e] = bf2f((ushort)e8[e]) + c;
    s += nv[e]; sq += nv[e] * nv[e];
  }
  bfx8 w8;
#pragma unroll
  for (int e = 0; e < 8; e++) w8[e] = (short)f2bf(nv[e]);
  *(bfx8*)ep = w8;
#pragma unroll
  for (int off = 8; off; off >>= 1) { s += __shfl_xor(s, off); sq += __shfl_xor(sq, off); }
  float m = s * (1.f / 128.f);
  float var = sq * (1.f / 128.f) - m * m;
  float rs = rsqrtf(var + 1e-5f);
  bfx8 r8;
#pragma unroll
  for (int e = 0; e < 8; e++) {
    int d = d0 + e;
    r8[e] = (short)f2bf((nv[e] - m) * rs * sw[d] + sb[d]);
  }
  *(bfx8*)(xn2 + (size_t)tok * 128 + d0) = r8;
}

// ---------------- in-proj GEMM + fused u: grid (M/128, 2) ----------------
__global__ __launch_bounds__(256) void k_gemm_xz(
    const ushort* __restrict__ A, const ushort* __restrict__ W, const float* __restrict__ bias,
    ushort* __restrict__ Zu, const ushort* __restrict__ xw, const float* __restrict__ xb,
    float* __restrict__ UT) {
  __shared__ ushort sl[128 * SLS];
  const int t = threadIdx.x;
  const int l = t & 63, wv = t >> 6;
  const int l15 = l & 15, q = l >> 4;
  const int wm = wv >> 1, wn = wv & 1;
  const int m0 = blockIdx.x * 128 + wm * 64;
  const int n0 = blockIdx.y * 128 + wn * 64;
  f32x4 acc[4][4] = {};
  const ushort* Ab = A + (size_t)(m0 + l15) * 128 + q * 8;
  const ushort* Wb = W + (size_t)(n0 + l15) * 128 + q * 8;
#pragma unroll
  for (int k0 = 0; k0 < 128; k0 += 32) {
    bfx8 a[4], b[4];
#pragma unroll
    for (int mf = 0; mf < 4; mf++) a[mf] = *(const bfx8*)(Ab + (size_t)mf * 16 * 128 + k0);
#pragma unroll
    for (int nf = 0; nf < 4; nf++) b[nf] = *(const bfx8*)(Wb + (size_t)nf * 16 * 128 + k0);
#pragma unroll
    for (int mf = 0; mf < 4; mf++)
#pragma unroll
      for (int nf = 0; nf < 4; nf++)
        acc[mf][nf] = __builtin_amdgcn_mfma_f32_16x16x32_bf16(a[mf], b[nf], acc[mf][nf], 0, 0, 0);
  }
  if (blockIdx.y == 1) {
#pragma unroll
    for (int mf = 0; mf < 4; mf++)
#pragma unroll
      for (int nf = 0; nf < 4; nf++) {
        const int col = n0 + nf * 16 + l15;
        const float bb = bias[col];
#pragma unroll
        for (int r = 0; r < 4; r++) {
          const int row = m0 + mf * 16 + q * 4 + r;
          float v = acc[mf][nf][r] + bb;
          Zu[(size_t)row * 128 + col - 128] = f2bf(1.f / (1.f + __expf(-v)));
        }
      }
    return;
  }
  // y==0: silu -> LDS tile
#pragma unroll
  for (int mf = 0; mf < 4; mf++)
#pragma unroll
    for (int nf = 0; nf < 4; nf++) {
      const int col = wn * 64 + nf * 16 + l15;
      const float bb = bias[col];
#pragma unroll
      for (int r = 0; r < 4; r++) {
        const int rowl = wm * 64 + mf * 16 + q * 4 + r;
        float v = acc[mf][nf][r] + bb;
        sl[rowl * SLS + col] = f2bf(v / (1.f + __expf(-v)));
      }
    }
  __syncthreads();
  // u-GEMM: M=128, N=16 (ds), K=128
  f32x4 pu[2] = {};
#pragma unroll
  for (int k0 = 0; k0 < 128; k0 += 32) {
    bfx8 bx_ = *(const bfx8*)(xw + l15 * 128 + k0 + q * 8);
#pragma unroll
    for (int mi = 0; mi < 2; mi++) {
      bfx8 a2 = *(const bfx8*)&sl[(wv * 32 + mi * 16 + l15) * SLS + k0 + q * 8];
      pu[mi] = __builtin_amdgcn_mfma_f32_16x16x32_bf16(a2, bx_, pu[mi], 0, 0, 0);
    }
  }
  const float ub = xb[l15];
#pragma unroll
  for (int mi = 0; mi < 2; mi++)
#pragma unroll
    for (int r = 0; r < 4; r++) {
      int token = blockIdx.x * 128 + wv * 32 + mi * 16 + q * 4 + r;
      int b = token >> 12, ll = token & 4095;
      UT[((size_t)(b * 16 + l15)) * 4096 + ll] = pu[mi][r] + ub;
    }
}

// ---------------- out-proj + residual + ln2 + mlp1(gelu): BM=64, grid M/64 ----------------
__global__ __launch_bounds__(256) void k_gemm_om(
    const ushort* __restrict__ A, const ushort* __restrict__ W1, const float* __restrict__ b1,
    ushort* __restrict__ emb, const float* __restrict__ lw, const float* __restrict__ lb,
    const ushort* __restrict__ W2, const float* __restrict__ b2, ushort* __restrict__ MH) {
  __shared__ ushort sl1[64 * SLS];
  __shared__ float red[2][64][2];
  const int t = threadIdx.x;
  const int l = t & 63, wv = t >> 6;
  const int l15 = l & 15, q = l >> 4;
  const int wm = wv >> 1, wn = wv & 1;
  const int m0 = blockIdx.x * 64;
  const int n0 = wn * 64;
  // ---- phase 1: out-proj 64x128 + residual + ln2 -> sl1
  {
    ushort epre[2][4][4];
#pragma unroll
    for (int mf = 0; mf < 2; mf++)
#pragma unroll
      for (int nf = 0; nf < 4; nf++)
#pragma unroll
        for (int r = 0; r < 4; r++)
          epre[mf][nf][r] = emb[(size_t)(m0 + wm * 32 + mf * 16 + q * 4 + r) * 128 + n0 + nf * 16 + l15];
    f32x4 acc[2][4] = {};
    const ushort* Ab = A + (size_t)(m0 + wm * 32 + l15) * 128 + q * 8;
    const ushort* Wb = W1 + (size_t)(n0 + l15) * 128 + q * 8;
#pragma unroll
    for (int k0 = 0; k0 < 128; k0 += 32) {
      bfx8 a[2], b[4];
#pragma unroll
      for (int mf = 0; mf < 2; mf++) a[mf] = *(const bfx8*)(Ab + (size_t)mf * 16 * 128 + k0);
#pragma unroll
      for (int nf = 0; nf < 4; nf++) b[nf] = *(const bfx8*)(Wb + (size_t)nf * 16 * 128 + k0);
#pragma unroll
      for (int mf = 0; mf < 2; mf++)
#pragma unroll
        for (int nf = 0; nf < 4; nf++)
          acc[mf][nf] = __builtin_amdgcn_mfma_f32_16x16x32_bf16(a[mf], b[nf], acc[mf][nf], 0, 0, 0);
    }
    float sv[2][4], qv[2][4];
#pragma unroll
    for (int mf = 0; mf < 2; mf++)
#pragma unroll
      for (int r = 0; r < 4; r++) { sv[mf][r] = 0.f; qv[mf][r] = 0.f; }
#pragma unroll
    for (int mf = 0; mf < 2; mf++)
#pragma unroll
      for (int nf = 0; nf < 4; nf++) {
        const int col = n0 + nf * 16 + l15;
        const float bb = b1[col];
#pragma unroll
        for (int r = 0; r < 4; r++) {
          float v = acc[mf][nf][r] + bb + bf2f(epre[mf][nf][r]);
          acc[mf][nf][r] = v;
          sv[mf][r] += v; qv[mf][r] += v * v;
        }
      }
#pragma unroll
    for (int mf = 0; mf < 2; mf++)
#pragma unroll
      for (int r = 0; r < 4; r++) {
#pragma unroll
        for (int off = 1; off < 16; off <<= 1) {
          sv[mf][r] += __shfl_xor(sv[mf][r], off);
          qv[mf][r] += __shfl_xor(qv[mf][r], off);
        }
        if (l15 == 0) {
          int rowl = wm * 32 + mf * 16 + q * 4 + r;
          red[0][rowl][wn] = sv[mf][r];
          red[1][rowl][wn] = qv[mf][r];
        }
      }
    __syncthreads();
#pragma unroll
    for (int mf = 0; mf < 2; mf++)
#pragma unroll
      for (int r = 0; r < 4; r++) {
        const int rowl = wm * 32 + mf * 16 + q * 4 + r;
        const int row = m0 + rowl;
        float ts = red[0][rowl][0] + red[0][rowl][1];
        float tq = red[1][rowl][0] + red[1][rowl][1];
        float mm = ts * (1.f / 128.f);
        float var = tq * (1.f / 128.f) - mm * mm;
        float rs = rsqrtf(var + 1e-5f);
#pragma unroll
        for (int nf = 0; nf < 4; nf++) {
          const int col = n0 + nf * 16 + l15;
          float v = acc[mf][nf][r];
          emb[(size_t)row * 128 + col] = f2bf(v);
          sl1[rowl * SLS + col] = f2bf((v - mm) * rs * lw[col] + lb[col]);
        }
      }
  }
  __syncthreads();
  // ---- phase 2: MH[64][256] = gelu(ln2 @ W2^T + b2); each wave owns a 64-col strip
  const int cw0 = wv * 64;
  f32x4 acc2[4][4] = {};
#pragma unroll
  for (int k0 = 0; k0 < 128; k0 += 32) {
    bfx8 a2[4];
#pragma unroll
    for (int mi = 0; mi < 4; mi++)
      a2[mi] = *(const bfx8*)&sl1[(mi * 16 + l15) * SLS + k0 + q * 8];
#pragma unroll
    for (int nf = 0; nf < 4; nf++) {
      bfx8 b2v = *(const bfx8*)(W2 + (size_t)(cw0 + nf * 16 + l15) * 128 + k0 + q * 8);
#pragma unroll
      for (int mi = 0; mi < 4; mi++)
        acc2[mi][nf] = __builtin_amdgcn_mfma_f32_16x16x32_bf16(a2[mi], b2v, acc2[mi][nf], 0, 0, 0);
    }
  }
#pragma unroll
  for (int mi = 0; mi < 4; mi++)
#pragma unroll
    for (int nf = 0; nf < 4; nf++) {
      const int col = cw0 + nf * 16 + l15;
      const float bb = b2[col];
#pragma unroll
      for (int r = 0; r < 4; r++) {
        const int row = m0 + mi * 16 + q * 4 + r;
        float v = acc2[mi][nf][r] + bb;
        MH[(size_t)row * 256 + col] = f2bf(gelu_fast(v));
      }
    }
}

// ---------------- MFMA GEMM (mlp2), BM=32 (8 blocks/CU for latency hiding):
//   MODE 5: emb+=v (bf16), LN -> out2v bf16 [M,128]
//   MODE 4: emb+=v (bf16), bf16 -> out2v channels-last at +128
// Each of 4 waves owns ALL 32 rows x a 32-col strip; LN partials via red[2][32][4].
// NOTE (MODE 4): out2v (U2C) ALIASES A (MH). __syncthreads() after K-loop REQUIRED
// (rows are block-disjoint, so inter-block is safe; barrier covers intra-block).
template <int MODE, int K>
__global__ __launch_bounds__(256) void k_mgemm(const ushort* __restrict__ A, const ushort* __restrict__ W,
                                               const float* __restrict__ bias, void* __restrict__ out2v,
                                               ushort* __restrict__ emb,
                                               const float* __restrict__ lw, const float* __restrict__ lb) {
  __shared__ float red[2][32][4];
  const int t = threadIdx.x;
  const int l = t & 63, wv = t >> 6;   // wv = 32-col strip index
  const int l15 = l & 15, q = l >> 4;
  const int m0 = blockIdx.x * 32;
  const int n0 = wv * 32;
  // prefetch residual (independent of K-loop)
  ushort epre[2][2][4];
#pragma unroll
  for (int mf = 0; mf < 2; mf++)
#pragma unroll
    for (int nf = 0; nf < 2; nf++)
#pragma unroll
      for (int r = 0; r < 4; r++)
        epre[mf][nf][r] = emb[(size_t)(m0 + mf * 16 + q * 4 + r) * 128 + n0 + nf * 16 + l15];
  f32x4 acc[2][2] = {};
  const ushort* Ab = A + (size_t)(m0 + l15) * K + q * 8;
  const ushort* Wb = W + (size_t)(n0 + l15) * K + q * 8;
#pragma unroll
  for (int k0 = 0; k0 < K; k0 += 32) {
    bfx8 a[2], b[2];
#pragma unroll
    for (int mf = 0; mf < 2; mf++) a[mf] = *(const bfx8*)(Ab + (size_t)mf * 16 * K + k0);
#pragma unroll
    for (int nf = 0; nf < 2; nf++) b[nf] = *(const bfx8*)(Wb + (size_t)nf * 16 * K + k0);
#pragma unroll
    for (int mf = 0; mf < 2; mf++)
#pragma unroll
      for (int nf = 0; nf < 2; nf++)
        acc[mf][nf] = __builtin_amdgcn_mfma_f32_16x16x32_bf16(a[mf], b[nf], acc[mf][nf], 0, 0, 0);
  }
  if constexpr (MODE == 4) __syncthreads();  // drain aliased MH reads (see NOTE)
  float sv[2][4], qv[2][4];
#pragma unroll
  for (int mf = 0; mf < 2; mf++)
#pragma unroll
    for (int r = 0; r < 4; r++) { sv[mf][r] = 0.f; qv[mf][r] = 0.f; }
#pragma unroll
  for (int mf = 0; mf < 2; mf++)
#pragma unroll
    for (int nf = 0; nf < 2; nf++) {
      const int col = n0 + nf * 16 + l15;
      const float bb = bias[col];
#pragma unroll
      for (int r = 0; r < 4; r++) {
        float v = acc[mf][nf][r] + bb + bf2f(epre[mf][nf][r]);
        acc[mf][nf][r] = v;
        sv[mf][r] += v; qv[mf][r] += v * v;
      }
    }
  if constexpr (MODE == 5) {
#pragma unroll
    for (int mf = 0; mf < 2; mf++)
#pragma unroll
      for (int r = 0; r < 4; r++) {
#pragma unroll
        for (int off = 1; off < 16; off <<= 1) {
          sv[mf][r] += __shfl_xor(sv[mf][r], off);
          qv[mf][r] += __shfl_xor(qv[mf][r], off);
        }
        if (l15 == 0) {
          int rowl = mf * 16 + q * 4 + r;   // 0..31
          red[0][rowl][wv] = sv[mf][r];
          red[1][rowl][wv] = qv[mf][r];
        }
      }
    __syncthreads();
  }
#pragma unroll
  for (int mf = 0; mf < 2; mf++)
#pragma unroll
    for (int r = 0; r < 4; r++) {
      const int rowl = mf * 16 + q * 4 + r;
      const int row = m0 + rowl;
      float mm = 0.f, rs = 0.f;
      if constexpr (MODE == 5) {
        float ts = red[0][rowl][0] + red[0][rowl][1] + red[0][rowl][2] + red[0][rowl][3];
        float tq = red[1][rowl][0] + red[1][rowl][1] + red[1][rowl][2] + red[1][rowl][3];
        mm = ts * (1.f / 128.f);
        float var = tq * (1.f / 128.f) - mm * mm;
        rs = rsqrtf(var + 1e-5f);
      }
#pragma unroll
      for (int nf = 0; nf < 2; nf++) {
        const int col = n0 + nf * 16 + l15;
        float v = acc[mf][nf][r];
        emb[(size_t)row * 128 + col] = f2bf(v);
        if constexpr (MODE == 5)
          ((ushort*)out2v)[(size_t)row * 128 + col] = f2bf((v - mm) * rs * lw[col] + lb[col]);
        else
          ((ushort*)out2v)[(size_t)row * 256 + 128 + col] = f2bf(v);
      }
    }
}

// ---------------- register chunked scan ----------------
__global__ __launch_bounds__(64) void k_scan(const float* __restrict__ UT, float* __restrict__ HST,
                                             const float* __restrict__ A_log) {
  const int b = blockIdx.x >> 4, ds = blockIdx.x & 15;
  const int tid = threadIdx.x;
  const float a = expf(-expf(A_log[ds]));   // keep libm: amplified through a^64
  const float4* ut4 = (const float4*)(UT + ((size_t)(b * 16 + ds)) * 4096 + tid * 64);
  float r[64];
#pragma unroll
  for (int j4 = 0; j4 < 16; j4++) {
    float4 v = ut4[j4];
    r[j4 * 4 + 0] = v.x; r[j4 * 4 + 1] = v.y; r[j4 * 4 + 2] = v.z; r[j4 * 4 + 3] = v.w;
  }
  float h = 0.f;
#pragma unroll
  for (int j = 0; j < 64; j++) { h = a * h + r[j]; r[j] = h; }
  float a64 = a;
#pragma unroll
  for (int qq = 0; qq < 6; qq++) a64 *= a64;
  float Ac = a64, Bc = h;
#pragma unroll
  for (int off = 1; off < 64; off <<= 1) {
    float Ap = __shfl_up(Ac, off);
    float Bp = __shfl_up(Bc, off);
    if (tid >= off) { Bc = Ac * Bp + Bc; Ac = Ac * Ap; }
  }
  float carry = __shfl_up(Bc, 1);
  if (tid == 0) carry = 0.f;
  float p = a;
#pragma unroll
  for (int j = 0; j < 64; j++) { r[j] += p * carry; p *= a; }
  float4* hb4 = (float4*)(HST + ((size_t)(b * 16 + ds)) * 4096 + tid * 64);
#pragma unroll
  for (int j4 = 0; j4 < 16; j4++) {
    float4 v; v.x = r[j4 * 4 + 0]; v.y = r[j4 * 4 + 1]; v.z = r[j4 * 4 + 2]; v.w = r[j4 * 4 + 3];
    hb4[j4] = v;
  }
}

// ---------------- y = (hs @ D) * z ----------------
__global__ __launch_bounds__(256) void k_yb(const float* __restrict__ HST, const float* __restrict__ Dm_,
                                            const ushort* __restrict__ Z, ushort* __restrict__ Y) {
  const int m = blockIdx.x * 2 + (threadIdx.x >> 7);
  const int d = threadIdx.x & 127;
  const int b = m >> 12, l = m & 4095;
  const float* hb = HST + (size_t)b * 16 * Ln + l;
  float acc = 0.f;
#pragma unroll
  for (int s = 0; s < 16; s++) acc += hb[(size_t)s * Ln] * Dm_[s * 128 + d];
  const size_t o = (size_t)m * 128 + d;
  Y[o] = f2bf(acc * bf2f(Z[o]));
}

// ---------------- LDS-staged implicit-GEMM conv (WPB waves/block) ----------------
template <int MODE, int OTH, int OTW, int CIN, int WPB>
__global__ __launch_bounds__(WPB * 64) void k_cv(
    const ushort* __restrict__ in, ushort* __restrict__ out,
    const ushort* __restrict__ wt, const float* __restrict__ bias,
    int Hi, int Wi, int CP, int CO, int CPo, int COo, int Cout,
    int nsp, int nspx, long ibs, long obs) {
  constexpr int ITH = (MODE == 1) ? (2 * OTH + 1) : (OTH + 2);
  constexpr int ITW = (MODE == 1) ? (2 * OTW + 1) : (OTW + 2);
  constexpr int NPIX = ITH * ITW;
  constexpr int SPF = OTH * OTW / 16;
  constexpr int NTAPS = (MODE == 2) ? 4 : 9;
  constexpr int NCH = CIN / 32;
  __shared__ __attribute__((aligned(16))) ushort lds[NPIX * 40];
  const int t = threadIdx.x;
  const int w = t >> 6, l = t & 63;
  const int l15 = l & 15, q = l >> 4;
  const int b = blockIdx.z;
  const int py = (MODE == 2) ? ((int)blockIdx.y >> 1) : 0;
  const int px = (MODE == 2) ? ((int)blockIdx.y & 1) : 0;
  const int cb = blockIdx.x / nsp;
  const int spt = blockIdx.x - cb * nsp;
  const int spy = spt / nspx, spx = spt - spy * nspx;
  const int n0 = cb * (16 * WPB) + w * 16;
  const int y0 = spy * OTH, x0 = spx * OTW;
  const int gy0 = (MODE == 1) ? (2 * y0 - 1) : (y0 - 1);
  const int gx0 = (MODE == 1) ? (2 * x0 - 1) : (x0 - 1);
  const ushort* ib = in + (size_t)b * ibs;
  f32x4 acc[SPF] = {};
  int abase[SPF];
#pragma unroll
  for (int af = 0; af < SPF; af++) {
    int p = af * 16 + l15;
    int ty = p / OTW, tx = p % OTW;
    int sy = (MODE == 1) ? (2 * ty) : ty;
    int sx = (MODE == 1) ? (2 * tx) : tx;
    abase[af] = (sy * ITW + sx) * 40 + q * 8;
  }
  for (int c = 0; c < NCH; c++) {
    const int k0 = c * 32;
    __syncthreads();
    for (int idx = t; idx < NPIX * 4; idx += WPB * 64) {
      int pix = idx >> 2, qq = idx & 3;
      int sy = pix / ITW, sx = pix - sy * ITW;
      int gy = gy0 + sy, gx = gx0 + sx;
      bfx8 v = {0, 0, 0, 0, 0, 0, 0, 0};
      if ((unsigned)gy < (unsigned)Hi && (unsigned)gx < (unsigned)Wi)
        v = *(const bfx8*)(ib + (size_t)(gy * Wi + gx) * CP + CO + k0 + qq * 8);
      *(bfx8*)&lds[pix * 40 + qq * 8] = v;
    }
    __syncthreads();
#pragma unroll
    for (int tap = 0; tap < NTAPS; tap++) {
      const int dy = (MODE == 2) ? (tap >> 1) : (tap / 3);
      const int dx = (MODE == 2) ? (tap & 1) : (tap - (tap / 3) * 3);
      const int tapw = (MODE == 2) ? ((3 - py - 2 * dy) * 4 + (3 - px - 2 * dx)) : tap;
      const int toff = (MODE == 2) ? (((py + dy) * ITW + (px + dx)) * 40)
                                   : ((dy * ITW + dx) * 40);
      bfx8 bv = *(const bfx8*)(wt + ((size_t)tapw * Cout + n0 + l15) * CIN + k0 + q * 8);
#pragma unroll
      for (int af = 0; af < SPF; af++) {
        bfx8 av = *(const bfx8*)&lds[abase[af] + toff];
        acc[af] = __builtin_amdgcn_mfma_f32_16x16x32_bf16(av, bv, acc[af], 0, 0, 0);
      }
    }
  }
  const float bb = bias[n0 + l15];
  ushort* ob = out + (size_t)b * obs + COo + n0 + l15;
#pragma unroll
  for (int af = 0; af < SPF; af++) {
#pragma unroll
    for (int r = 0; r < 4; r++) {
      int p = af * 16 + q * 4 + r;
      int ty = p / OTW, tx = p % OTW;
      int oy, ox, Wo;
      if (MODE == 2) { oy = (y0 + ty) * 2 + py; ox = (x0 + tx) * 2 + px; Wo = Wi * 2; }
      else if (MODE == 1) { oy = y0 + ty; ox = x0 + tx; Wo = Wi / 2; }
      else { oy = y0 + ty; ox = x0 + tx; Wo = Wi; }
      ob[(size_t)(oy * Wo + ox) * CPo] = f2bf(fmaxf(acc[af][r] + bb, 0.f));
    }
  }
}

// ---------------- final 1x1 conv 256 -> 2, wave-per-row shuffle reduce ----------------
__global__ __launch_bounds__(256) void k_final3(const ushort* __restrict__ in, const float* __restrict__ w,
                                                const float* __restrict__ bias, float* __restrict__ out) {
  int wid = (blockIdx.x << 2) + (threadIdx.x >> 6); // row 0..65535
  int lane = threadIdx.x & 63;
  const ushort* rp = in + (size_t)wid * 256 + lane * 4;
  ushort4 u = *(const ushort4*)rp;
  float f0 = bf2f(u.x), f1 = bf2f(u.y), f2 = bf2f(u.z), f3 = bf2f(u.w);
  float4 w0 = *(const float4*)(w + lane * 4);
  float4 w1 = *(const float4*)(w + 256 + lane * 4);
  float a0 = f0 * w0.x + f1 * w0.y + f2 * w0.z + f3 * w0.w;
  float a1 = f0 * w1.x + f1 * w1.y + f2 * w1.z + f3 * w1.w;
#pragma unroll
  for (int off = 32; off; off >>= 1) { a0 += __shfl_xor(a0, off); a1 += __shfl_xor(a1, off); }
  if (lane == 0) {
    int b = wid >> 12, p = wid & 4095;
    out[(size_t)b * 8192 + p] = a0 + bias[0];
    out[(size_t)b * 8192 + 4096 + p] = a1 + bias[1];
  }
}

extern "C" void kernel_launch(void* const* d_in, const int* in_sizes, int n_in,
                              void* d_out, int out_size, void* d_ws, size_t ws_size,
                              hipStream_t stream) {
  (void)in_sizes; (void)n_in; (void)out_size; (void)ws_size;
  const float* x          = (const float*)d_in[0];
  const float* emb_w      = (const float*)d_in[1];
  const float* emb_b      = (const float*)d_in[2];
  const float* pos_embed  = (const float*)d_in[3];
  const float* time_embed = (const float*)d_in[4];
  const float* blk_ln1_w  = (const float*)d_in[5];
  const float* blk_ln1_b  = (const float*)d_in[6];
  const float* blk_conv_w = (const float*)d_in[7];
  const float* blk_conv_b = (const float*)d_in[8];
  const float* blk_sln_w  = (const float*)d_in[9];
  const float* blk_sln_b  = (const float*)d_in[10];
  const float* blk_A_log  = (const float*)d_in[11];
  const float* blk_D      = (const float*)d_in[12];
  const float* blk_in_w   = (const float*)d_in[13];
  const float* blk_in_b   = (const float*)d_in[14];
  const float* blk_x_w    = (const float*)d_in[15];
  const float* blk_x_b    = (const float*)d_in[16];
  const float* blk_out_w  = (const float*)d_in[17];
  const float* blk_out_b  = (const float*)d_in[18];
  const float* blk_ln2_w  = (const float*)d_in[19];
  const float* blk_ln2_b  = (const float*)d_in[20];
  const float* blk_mlp_w1 = (const float*)d_in[21];
  const float* blk_mlp_b1 = (const float*)d_in[22];
  const float* blk_mlp_w2 = (const float*)d_in[23];
  const float* blk_mlp_b2 = (const float*)d_in[24];
  const float* down1_w    = (const float*)d_in[25];
  const float* down1_b    = (const float*)d_in[26];
  const float* down2_w    = (const float*)d_in[27];
  const float* down2_b    = (const float*)d_in[28];
  const float* bott_w     = (const float*)d_in[29];
  const float* bott_b     = (const float*)d_in[30];
  const float* up1_w      = (const float*)d_in[31];
  const float* up1_b      = (const float*)d_in[32];
  const float* up2_w      = (const float*)d_in[33];
  const float* up2_b      = (const float*)d_in[34];
  const float* final_w    = (const float*)d_in[35];
  const float* final_b    = (const float*)d_in[36];

  // workspace layout (float offsets, F = 1Mi floats):
  //  EMBh 0-4F (bf16) | XN1 8-12F | XN2 12-16F | MH/U2C 16-24F | Zu 24-28F
  //  W3+CWT 28-29.2F | Ubuf 32-33F | HST 33-34F      (no overlaps!)
  float* ws = (float*)d_ws;
  constexpr size_t F = 1u << 20;
  ushort* EMBh = (ushort*)ws;                 // bf16 residual [M,128]
  ushort* XN1 = (ushort*)(ws + 8 * F);        // ln1-out bf16 [M,128]
  ushort* XN2 = XN1 + 8 * F;                  // sln-out / y bf16 [M,128]
  ushort* MH  = (ushort*)(ws + 16 * F);       // mlp hidden bf16 [M,256] / U2C
  ushort* Zu  = (ushort*)(ws + 24 * F);       // z bf16 [M,128]
  ushort* W3  = (ushort*)(ws + 28 * F);       // preprocessed weights
  float* Ubuf = ws + 32 * F;                  // xc scratch, then U_T fp32
  float* HST  = ws + 33 * F;                  // hs^T fp32

  // W3 offsets (ushorts)
  ushort* Wi  = W3;                 // 2*256*128
  ushort* Wo  = W3 + 65536;         // 2*128*128
  ushort* Wm1 = W3 + 98304;         // 2*256*128
  ushort* Wm2 = W3 + 163840;        // 2*128*256
  ushort* Wx  = W3 + 229376;        // 2*16*128
  ushort* Wd1 = W3 + 233472;        // 9*128*128
  ushort* Wd2 = W3 + 380928;        // 9*256*128
  ushort* Wb9 = W3 + 675840;        // 9*256*256
  ushort* Wu1 = W3 + 1265664;       // 16*128*256
  ushort* Wu2 = W3 + 1789952;       // 16*128*256
  float*  CWT = (float*)(W3 + 2314240); // 2*4*128 fp32

  k_prep<<<9044, 256, 0, stream>>>(blk_in_w, blk_out_w, blk_mlp_w1, blk_mlp_w2, blk_x_w,
                                   blk_conv_w, down1_w, down2_w, bott_w, up1_w, up2_w, W3, CWT);
  k_combine<<<256, 256, 0, stream>>>(x, Ubuf);
  k_embedln<<<8192, 256, 0, stream>>>(Ubuf, emb_w, emb_b, pos_embed, time_embed,
                                      blk_ln1_w, blk_ln1_b, EMBh, XN1);

  ushort* U2C = MH; // [B,64,64,256] channels-last (written by mlp2 MODE4 + up2)
  for (int i = 0; i < 2; i++) {
    k_fuse1<<<4096, 256, 0, stream>>>(XN1, EMBh, XN2, CWT + i * 512, blk_conv_b + i * Dn,
                                      blk_sln_w + i * Dn, blk_sln_b + i * Dn);
    k_gemm_xz<<<dim3(512, 2), 256, 0, stream>>>(XN2, Wi + i * 32768, blk_in_b + i * 256,
                                                Zu, Wx + i * 2048, blk_x_b + i * DSn, Ubuf);
    k_scan<<<256, 64, 0, stream>>>(Ubuf, HST, blk_A_log + i * DSn);
    k_yb<<<32768, 256, 0, stream>>>(HST, blk_D + i * DSn * Dn, Zu, XN2);
    k_gemm_om<<<1024, 256, 0, stream>>>(XN2, Wo + i * 16384, blk_out_b + i * Dn,
                                        EMBh, blk_ln2_w + i * Dn, blk_ln2_b + i * Dn,
                                        Wm1 + i * 32768, blk_mlp_b1 + i * 256, MH);
    if (i == 0)
      k_mgemm<5, 256><<<2048, 256, 0, stream>>>(MH, Wm2 + i * 32768, blk_mlp_b2 + i * Dn,
                                                XN1, EMBh, blk_ln1_w + Dn, blk_ln1_b + Dn);
    else
      k_mgemm<4, 256><<<2048, 256, 0, stream>>>(MH, Wm2 + i * 32768, blk_mlp_b2 + i * Dn,
                                                U2C, EMBh, nullptr, nullptr);
  }

  // ---- UNet head, channels-last bf16 ----
  ushort* U1C = XN1;              // [B,32,32,256] (dead XN1 region)
  ushort* X2b = XN1 + 8388608;    // [B,16,16,256] (dead XN2 region)
  ushort* X3b = X2b + 1048576;    // [B,16,16,256]

  k_cv<1, 8, 8, 128, 4><<<dim3(2 * 16, 1, 16), 256, 0, stream>>>(
      U2C, U1C, Wd1, down1_b, 64, 64, 256, 128, 256, 128, 128,
      16, 4, 64L * 64 * 256, 32L * 32 * 256);
  k_cv<1, 8, 8, 128, 2><<<dim3(8 * 4, 1, 16), 128, 0, stream>>>(
      U1C, X2b, Wd2, down2_b, 32, 32, 256, 128, 256, 0, 256,
      4, 2, 32L * 32 * 256, 16L * 16 * 256);
  k_cv<0, 8, 8, 256, 2><<<dim3(8 * 4, 1, 16), 128, 0, stream>>>(
      X2b, X3b, Wb9, bott_b, 16, 16, 256, 0, 256, 0, 256,
      4, 2, 16L * 16 * 256, 16L * 16 * 256);
  k_cv<2, 8, 16, 256, 2><<<dim3(4 * 2, 4, 16), 128, 0, stream>>>(
      X3b, U1C, Wu1, up1_b, 16, 16, 256, 0, 256, 0, 128,
      2, 1, 16L * 16 * 256, 32L * 32 * 256);
  k_cv<2, 16, 16, 256, 4><<<dim3(2 * 4, 4, 16), 256, 0, stream>>>(
      U1C, U2C, Wu2, up2_b, 32, 32, 256, 0, 256, 0, 128,
      4, 2, 32L * 32 * 256, 64L * 64 * 256);

  k_final3<<<16384, 256, 0, stream>>>(U2C, final_w, final_b, (float*)d_out);
}

// Round 16
// 475.092 us; speedup vs baseline: 1.0247x; 1.0247x over previous
//
#include <hip/hip_runtime.h>
#include <hip/hip_bf16.h>
#include <cmath>

namespace {
constexpr int Bn = 16, Ln = 4096, Dn = 128, DSn = 16;
constexpr int Mtok = Bn * Ln; // 65536 tokens
constexpr int SLS = 138;      // LDS row stride (ushorts) for 128-col bf16 tiles
}

typedef short bfx8 __attribute__((ext_vector_type(8)));
typedef float f32x4 __attribute__((ext_vector_type(4)));

// hardware bf16 convert (RNE)
static __device__ __forceinline__ ushort f2bf(float f) {
  union { __hip_bfloat16 h; ushort u; } c;
  c.h = __float2bfloat16(f);
  return c.u;
}
static __device__ __forceinline__ float bf2f(ushort u) {
  union { unsigned u; float f; } v; v.u = ((unsigned)u) << 16;
  return v.f;
}
// tanh-form gelu with native exp
static __device__ __forceinline__ float gelu_fast(float x) {
  float u = x * (1.5957691216f + 0.07135481f * x * x);
  return x / (1.f + __expf(-u));
}

// ---------------- all weight preprocessing in one kernel ----------------
__global__ void k_prep(const float* __restrict__ inw, const float* __restrict__ outw,
                       const float* __restrict__ m1, const float* __restrict__ m2,
                       const float* __restrict__ xw, const float* __restrict__ cw,
                       const float* __restrict__ d1, const float* __restrict__ d2,
                       const float* __restrict__ bo, const float* __restrict__ u1,
                       const float* __restrict__ u2, ushort* __restrict__ W3,
                       float* __restrict__ CWT) {
  int i = blockIdx.x * 256 + threadIdx.x;
  if (i < 65536) { W3[i] = f2bf(inw[i]); return; }
  if (i < 98304) { W3[i] = f2bf(outw[i - 65536]); return; }
  if (i < 163840) { W3[i] = f2bf(m1[i - 98304]); return; }
  if (i < 229376) { W3[i] = f2bf(m2[i - 163840]); return; }
  if (i < 233472) { W3[i] = f2bf(xw[i - 229376]); return; }
  if (i < 234496) {
    int j = i - 233472; int blk = j >> 9, r = j & 511, d = r >> 2, k = r & 3;
    CWT[blk * 512 + k * 128 + d] = cw[j]; return;
  }
  if (i < 381952) { // down1: w[co][ci][9], 128->128
    int j = i - 234496; int co = j / (128 * 9); int r = j - co * (128 * 9);
    int ci = r / 9, tap = r - ci * 9;
    W3[233472 + ((size_t)tap * 128 + co) * 128 + ci] = f2bf(d1[j]); return;
  }
  if (i < 676864) { // down2: 128->256
    int j = i - 381952; int co = j / (128 * 9); int r = j - co * (128 * 9);
    int ci = r / 9, tap = r - ci * 9;
    W3[380928 + ((size_t)tap * 256 + co) * 128 + ci] = f2bf(d2[j]); return;
  }
  if (i < 1266688) { // bott: 256->256
    int j = i - 676864; int co = j / (256 * 9); int r = j - co * (256 * 9);
    int ci = r / 9, tap = r - ci * 9;
    W3[675840 + ((size_t)tap * 256 + co) * 256 + ci] = f2bf(bo[j]); return;
  }
  if (i < 1790976) { // up1: w[ci][co][16], 256->128
    int j = i - 1266688; int ci = j / (128 * 16); int r = j - ci * (128 * 16);
    int co = r >> 4, tap = r & 15;
    W3[1265664 + ((size_t)tap * 128 + co) * 256 + ci] = f2bf(u1[j]); return;
  }
  if (i < 2315264) { // up2
    int j = i - 1790976; int ci = j / (128 * 16); int r = j - ci * (128 * 16);
    int co = r >> 4, tap = r & 15;
    W3[1789952 + ((size_t)tap * 128 + co) * 256 + ci] = f2bf(u2[j]); return;
  }
}

// ---------------- embedding ----------------
__global__ void k_combine(const float* __restrict__ x, float* __restrict__ xc) {
  int i = blockIdx.x * 256 + threadIdx.x; // B*HW = 65536
  int b = i >> 12, p = i & 4095;
  const float* xb = x + (size_t)b * 5 * Ln + p;
  xc[i] = 0.5f * (xb[0] + xb[Ln] + xb[2 * Ln] + xb[3 * Ln]) + xb[4 * Ln];
}

// embed + ln1 fused: writes EMB (bf16 residual stream) and XN1 = ln1(EMB) bf16
__global__ __launch_bounds__(256) void k_embedln(
    const float* __restrict__ xc, const float* __restrict__ ew, const float* __restrict__ eb,
    const float* __restrict__ pos, const float* __restrict__ te,
    const float* __restrict__ lw, const float* __restrict__ lb,
    ushort* __restrict__ emb, ushort* __restrict__ xn) {
  int tok = blockIdx.x * 8 + (threadIdx.x >> 5);
  int ln = threadIdx.x & 31;
  int b = tok >> 12, l = tok & 4095;
  int h = l >> 6, w = l & 63;
  const float* xb = xc + b * 4096;
  float v[9];
#pragma unroll
  for (int dy = 0; dy < 3; dy++)
#pragma unroll
    for (int dx = 0; dx < 3; dx++) {
      int y = h + dy - 1, xx = w + dx - 1;
      v[dy * 3 + dx] = (y >= 0 && y < 64 && xx >= 0 && xx < 64) ? xb[y * 64 + xx] : 0.f;
    }
  int d0 = ln * 4;
  float o[4]; float s = 0.f, sq = 0.f;
#pragma unroll
  for (int e = 0; e < 4; e++) {
    int d = d0 + e;
    float a = 0.f;
#pragma unroll
    for (int k = 0; k < 9; k++) a += v[k] * ew[d * 9 + k];
    float ts = 0.5f * (te[d] + te[128 + d] + te[256 + d] + te[384 + d]) + te[512 + d];
    float r = a + 3.f * eb[d] + 3.f * pos[l * 128 + d] + ts;
    o[e] = r; s += r; sq += r * r;
  }
  ushort4 eo;
  eo.x = f2bf(o[0]); eo.y = f2bf(o[1]); eo.z = f2bf(o[2]); eo.w = f2bf(o[3]);
  *(ushort4*)(emb + (size_t)tok * 128 + d0) = eo;
#pragma unroll
  for (int off = 16; off; off >>= 1) { s += __shfl_xor(s, off); sq += __shfl_xor(sq, off); }
  float m = s * (1.f / 128.f);
  float var = sq * (1.f / 128.f) - m * m;
  float rs = rsqrtf(var + 1e-5f);
  ushort4 u;
  u.x = f2bf((o[0] - m) * rs * lw[d0 + 0] + lb[d0 + 0]);
  u.y = f2bf((o[1] - m) * rs * lw[d0 + 1] + lb[d0 + 1]);
  u.z = f2bf((o[2] - m) * rs * lw[d0 + 2] + lb[d0 + 2]);
  u.w = f2bf((o[3] - m) * rs * lw[d0 + 3] + lb[d0 + 3]);
  *(ushort4*)(xn + (size_t)tok * 128 + d0) = u;
}

// ---------------- fused dwconv + residual + sln (bf16 residual) ----------------
__global__ __launch_bounds__(256) void k_fuse1(
    const ushort* __restrict__ xn1, ushort* __restrict__ emb, ushort* __restrict__ xn2,
    const float* __restrict__ cwT, const float* __restrict__ cb,
    const float* __restrict__ sw, const float* __restrict__ sb) {
  int i = blockIdx.x * 256 + threadIdx.x; // Mtok*16
  int g = i & 15, tok = i >> 4, d0 = g * 8, l = tok & 4095;
  const ushort* p = xn1 + (size_t)tok * 128 + d0;
  const bfx8 zf = {0, 0, 0, 0, 0, 0, 0, 0};
  bfx8 v0 = *(const bfx8*)p;
  bfx8 v1 = (l >= 1) ? *(const bfx8*)(p - 128) : zf;
  bfx8 v2 = (l >= 2) ? *(const bfx8*)(p - 256) : zf;
  bfx8 v3 = (l >= 3) ? *(const bfx8*)(p - 384) : zf;
  ushort* ep = emb + (size_t)tok * 128 + d0;
  bfx8 e8 = *(const bfx8*)ep;
  float nv[8]; float s = 0.f, sq = 0.f;
#pragma unroll
  for (int e = 0; e < 8; e++) {
    int d = d0 + e;
    float c = cb[d] + cwT[3 * 128 + d] * bf2f((ushort)v0[e]) + cwT[2 * 128 + d] * bf2f((ushort)v1[e]) +
              cwT[1 * 128 + d] * bf2f((ushort)v2[e]) + cwT[0 * 128 + d] * bf2f((ushort)v3[e]);
    nv[e] = bf2f((ushort)e8[e]) + c;
    s += nv[e]; sq += nv[e] * nv[e];
  }
  bfx8 w8;
#pragma unroll
  for (int e = 0; e < 8; e++) w8[e] = (short)f2bf(nv[e]);
  *(bfx8*)ep = w8;
#pragma unroll
  for (int off = 8; off; off >>= 1) { s += __shfl_xor(s, off); sq += __shfl_xor(sq, off); }
  float m = s * (1.f / 128.f);
  float var = sq * (1.f / 128.f) - m * m;
  float rs = rsqrtf(var + 1e-5f);
  bfx8 r8;
#pragma unroll
  for (int e = 0; e < 8; e++) {
    int d = d0 + e;
    r8[e] = (short)f2bf((nv[e] - m) * rs * sw[d] + sb[d]);
  }
  *(bfx8*)(xn2 + (size_t)tok * 128 + d0) = r8;
}

// ---------------- in-proj GEMM + fused u: grid (M/128, 2) ----------------
__global__ __launch_bounds__(256) void k_gemm_xz(
    const ushort* __restrict__ A, const ushort* __restrict__ W, const float* __restrict__ bias,
    ushort* __restrict__ Zu, const ushort* __restrict__ xw, const float* __restrict__ xb,
    float* __restrict__ UT) {
  __shared__ ushort sl[128 * SLS];
  const int t = threadIdx.x;
  const int l = t & 63, wv = t >> 6;
  const int l15 = l & 15, q = l >> 4;
  const int wm = wv >> 1, wn = wv & 1;
  const int m0 = blockIdx.x * 128 + wm * 64;
  const int n0 = blockIdx.y * 128 + wn * 64;
  f32x4 acc[4][4] = {};
  const ushort* Ab = A + (size_t)(m0 + l15) * 128 + q * 8;
  const ushort* Wb = W + (size_t)(n0 + l15) * 128 + q * 8;
#pragma unroll
  for (int k0 = 0; k0 < 128; k0 += 32) {
    bfx8 a[4], b[4];
#pragma unroll
    for (int mf = 0; mf < 4; mf++) a[mf] = *(const bfx8*)(Ab + (size_t)mf * 16 * 128 + k0);
#pragma unroll
    for (int nf = 0; nf < 4; nf++) b[nf] = *(const bfx8*)(Wb + (size_t)nf * 16 * 128 + k0);
#pragma unroll
    for (int mf = 0; mf < 4; mf++)
#pragma unroll
      for (int nf = 0; nf < 4; nf++)
        acc[mf][nf] = __builtin_amdgcn_mfma_f32_16x16x32_bf16(a[mf], b[nf], acc[mf][nf], 0, 0, 0);
  }
  if (blockIdx.y == 1) {
#pragma unroll
    for (int mf = 0; mf < 4; mf++)
#pragma unroll
      for (int nf = 0; nf < 4; nf++) {
        const int col = n0 + nf * 16 + l15;
        const float bb = bias[col];
#pragma unroll
        for (int r = 0; r < 4; r++) {
          const int row = m0 + mf * 16 + q * 4 + r;
          float v = acc[mf][nf][r] + bb;
          Zu[(size_t)row * 128 + col - 128] = f2bf(1.f / (1.f + __expf(-v)));
        }
      }
    return;
  }
  // y==0: silu -> LDS tile
#pragma unroll
  for (int mf = 0; mf < 4; mf++)
#pragma unroll
    for (int nf = 0; nf < 4; nf++) {
      const int col = wn * 64 + nf * 16 + l15;
      const float bb = bias[col];
#pragma unroll
      for (int r = 0; r < 4; r++) {
        const int rowl = wm * 64 + mf * 16 + q * 4 + r;
        float v = acc[mf][nf][r] + bb;
        sl[rowl * SLS + col] = f2bf(v / (1.f + __expf(-v)));
      }
    }
  __syncthreads();
  // u-GEMM: M=128, N=16 (ds), K=128
  f32x4 pu[2] = {};
#pragma unroll
  for (int k0 = 0; k0 < 128; k0 += 32) {
    bfx8 bx_ = *(const bfx8*)(xw + l15 * 128 + k0 + q * 8);
#pragma unroll
    for (int mi = 0; mi < 2; mi++) {
      bfx8 a2 = *(const bfx8*)&sl[(wv * 32 + mi * 16 + l15) * SLS + k0 + q * 8];
      pu[mi] = __builtin_amdgcn_mfma_f32_16x16x32_bf16(a2, bx_, pu[mi], 0, 0, 0);
    }
  }
  const float ub = xb[l15];
#pragma unroll
  for (int mi = 0; mi < 2; mi++)
#pragma unroll
    for (int r = 0; r < 4; r++) {
      int token = blockIdx.x * 128 + wv * 32 + mi * 16 + q * 4 + r;
      int b = token >> 12, ll = token & 4095;
      UT[((size_t)(b * 16 + l15)) * 4096 + ll] = pu[mi][r] + ub;
    }
}

// ---------------- out-proj + residual + ln2 + mlp1(gelu): BM=64, grid M/64 ----------------
__global__ __launch_bounds__(256) void k_gemm_om(
    const ushort* __restrict__ A, const ushort* __restrict__ W1, const float* __restrict__ b1,
    ushort* __restrict__ emb, const float* __restrict__ lw, const float* __restrict__ lb,
    const ushort* __restrict__ W2, const float* __restrict__ b2, ushort* __restrict__ MH) {
  __shared__ ushort sl1[64 * SLS];
  __shared__ float red[2][64][2];
  const int t = threadIdx.x;
  const int l = t & 63, wv = t >> 6;
  const int l15 = l & 15, q = l >> 4;
  const int wm = wv >> 1, wn = wv & 1;
  const int m0 = blockIdx.x * 64;
  const int n0 = wn * 64;
  // ---- phase 1: out-proj 64x128 + residual + ln2 -> sl1
  {
    ushort epre[2][4][4];
#pragma unroll
    for (int mf = 0; mf < 2; mf++)
#pragma unroll
      for (int nf = 0; nf < 4; nf++)
#pragma unroll
        for (int r = 0; r < 4; r++)
          epre[mf][nf][r] = emb[(size_t)(m0 + wm * 32 + mf * 16 + q * 4 + r) * 128 + n0 + nf * 16 + l15];
    f32x4 acc[2][4] = {};
    const ushort* Ab = A + (size_t)(m0 + wm * 32 + l15) * 128 + q * 8;
    const ushort* Wb = W1 + (size_t)(n0 + l15) * 128 + q * 8;
#pragma unroll
    for (int k0 = 0; k0 < 128; k0 += 32) {
      bfx8 a[2], b[4];
#pragma unroll
      for (int mf = 0; mf < 2; mf++) a[mf] = *(const bfx8*)(Ab + (size_t)mf * 16 * 128 + k0);
#pragma unroll
      for (int nf = 0; nf < 4; nf++) b[nf] = *(const bfx8*)(Wb + (size_t)nf * 16 * 128 + k0);
#pragma unroll
      for (int mf = 0; mf < 2; mf++)
#pragma unroll
        for (int nf = 0; nf < 4; nf++)
          acc[mf][nf] = __builtin_amdgcn_mfma_f32_16x16x32_bf16(a[mf], b[nf], acc[mf][nf], 0, 0, 0);
    }
    float sv[2][4], qv[2][4];
#pragma unroll
    for (int mf = 0; mf < 2; mf++)
#pragma unroll
      for (int r = 0; r < 4; r++) { sv[mf][r] = 0.f; qv[mf][r] = 0.f; }
#pragma unroll
    for (int mf = 0; mf < 2; mf++)
#pragma unroll
      for (int nf = 0; nf < 4; nf++) {
        const int col = n0 + nf * 16 + l15;
        const float bb = b1[col];
#pragma unroll
        for (int r = 0; r < 4; r++) {
          float v = acc[mf][nf][r] + bb + bf2f(epre[mf][nf][r]);
          acc[mf][nf][r] = v;
          sv[mf][r] += v; qv[mf][r] += v * v;
        }
      }
#pragma unroll
    for (int mf = 0; mf < 2; mf++)
#pragma unroll
      for (int r = 0; r < 4; r++) {
#pragma unroll
        for (int off = 1; off < 16; off <<= 1) {
          sv[mf][r] += __shfl_xor(sv[mf][r], off);
          qv[mf][r] += __shfl_xor(qv[mf][r], off);
        }
        if (l15 == 0) {
          int rowl = wm * 32 + mf * 16 + q * 4 + r;
          red[0][rowl][wn] = sv[mf][r];
          red[1][rowl][wn] = qv[mf][r];
        }
      }
    __syncthreads();
#pragma unroll
    for (int mf = 0; mf < 2; mf++)
#pragma unroll
      for (int r = 0; r < 4; r++) {
        const int rowl = wm * 32 + mf * 16 + q * 4 + r;
        const int row = m0 + rowl;
        float ts = red[0][rowl][0] + red[0][rowl][1];
        float tq = red[1][rowl][0] + red[1][rowl][1];
        float mm = ts * (1.f / 128.f);
        float var = tq * (1.f / 128.f) - mm * mm;
        float rs = rsqrtf(var + 1e-5f);
#pragma unroll
        for (int nf = 0; nf < 4; nf++) {
          const int col = n0 + nf * 16 + l15;
          float v = acc[mf][nf][r];
          emb[(size_t)row * 128 + col] = f2bf(v);
          sl1[rowl * SLS + col] = f2bf((v - mm) * rs * lw[col] + lb[col]);
        }
      }
  }
  __syncthreads();
  // ---- phase 2: MH[64][256] = gelu(ln2 @ W2^T + b2); each wave owns a 64-col strip
  const int cw0 = wv * 64;
  f32x4 acc2[4][4] = {};
#pragma unroll
  for (int k0 = 0; k0 < 128; k0 += 32) {
    bfx8 a2[4];
#pragma unroll
    for (int mi = 0; mi < 4; mi++)
      a2[mi] = *(const bfx8*)&sl1[(mi * 16 + l15) * SLS + k0 + q * 8];
#pragma unroll
    for (int nf = 0; nf < 4; nf++) {
      bfx8 b2v = *(const bfx8*)(W2 + (size_t)(cw0 + nf * 16 + l15) * 128 + k0 + q * 8);
#pragma unroll
      for (int mi = 0; mi < 4; mi++)
        acc2[mi][nf] = __builtin_amdgcn_mfma_f32_16x16x32_bf16(a2[mi], b2v, acc2[mi][nf], 0, 0, 0);
    }
  }
#pragma unroll
  for (int mi = 0; mi < 4; mi++)
#pragma unroll
    for (int nf = 0; nf < 4; nf++) {
      const int col = cw0 + nf * 16 + l15;
      const float bb = b2[col];
#pragma unroll
      for (int r = 0; r < 4; r++) {
        const int row = m0 + mi * 16 + q * 4 + r;
        float v = acc2[mi][nf][r] + bb;
        MH[(size_t)row * 256 + col] = f2bf(gelu_fast(v));
      }
    }
}

// ---------------- MFMA GEMM (mlp2), BM=64: MODE 5: emb+=v (bf16), LN -> out2v bf16 [M,128]
//                                         MODE 4: emb+=v (bf16), bf16 -> out2v channels-last at +128
// NOTE (MODE 4): out2v (U2C) ALIASES A (MH). __syncthreads() after K-loop REQUIRED.
template <int MODE, int K>
__global__ __launch_bounds__(256) void k_mgemm(const ushort* __restrict__ A, const ushort* __restrict__ W,
                                               const float* __restrict__ bias, void* __restrict__ out2v,
                                               ushort* __restrict__ emb,
                                               const float* __restrict__ lw, const float* __restrict__ lb) {
  __shared__ float red[2][64][2];
  const int t = threadIdx.x;
  const int l = t & 63, wv = t >> 6;
  const int l15 = l & 15, q = l >> 4;
  const int wm = wv >> 1, wn = wv & 1;
  const int m0 = blockIdx.x * 64;
  const int n0 = wn * 64;
  // prefetch residual (independent of K-loop)
  ushort epre[2][4][4];
#pragma unroll
  for (int mf = 0; mf < 2; mf++)
#pragma unroll
    for (int nf = 0; nf < 4; nf++)
#pragma unroll
      for (int r = 0; r < 4; r++)
        epre[mf][nf][r] = emb[(size_t)(m0 + wm * 32 + mf * 16 + q * 4 + r) * 128 + n0 + nf * 16 + l15];
  f32x4 acc[2][4] = {};
  const ushort* Ab = A + (size_t)(m0 + wm * 32 + l15) * K + q * 8;
  const ushort* Wb = W + (size_t)(n0 + l15) * K + q * 8;
#pragma unroll
  for (int k0 = 0; k0 < K; k0 += 32) {
    bfx8 a[2], b[4];
#pragma unroll
    for (int mf = 0; mf < 2; mf++) a[mf] = *(const bfx8*)(Ab + (size_t)mf * 16 * K + k0);
#pragma unroll
    for (int nf = 0; nf < 4; nf++) b[nf] = *(const bfx8*)(Wb + (size_t)nf * 16 * K + k0);
#pragma unroll
    for (int mf = 0; mf < 2; mf++)
#pragma unroll
      for (int nf = 0; nf < 4; nf++)
        acc[mf][nf] = __builtin_amdgcn_mfma_f32_16x16x32_bf16(a[mf], b[nf], acc[mf][nf], 0, 0, 0);
  }
  if constexpr (MODE == 4) __syncthreads();  // drain aliased MH reads (see NOTE)
  float sv[2][4], qv[2][4];
#pragma unroll
  for (int mf = 0; mf < 2; mf++)
#pragma unroll
    for (int r = 0; r < 4; r++) { sv[mf][r] = 0.f; qv[mf][r] = 0.f; }
#pragma unroll
  for (int mf = 0; mf < 2; mf++)
#pragma unroll
    for (int nf = 0; nf < 4; nf++) {
      const int col = n0 + nf * 16 + l15;
      const float bb = bias[col];
#pragma unroll
      for (int r = 0; r < 4; r++) {
        float v = acc[mf][nf][r] + bb + bf2f(epre[mf][nf][r]);
        acc[mf][nf][r] = v;
        sv[mf][r] += v; qv[mf][r] += v * v;
      }
    }
  if constexpr (MODE == 5) {
#pragma unroll
    for (int mf = 0; mf < 2; mf++)
#pragma unroll
      for (int r = 0; r < 4; r++) {
#pragma unroll
        for (int off = 1; off < 16; off <<= 1) {
          sv[mf][r] += __shfl_xor(sv[mf][r], off);
          qv[mf][r] += __shfl_xor(qv[mf][r], off);
        }
        if (l15 == 0) {
          int rowl = wm * 32 + mf * 16 + q * 4 + r;
          red[0][rowl][wn] = sv[mf][r];
          red[1][rowl][wn] = qv[mf][r];
        }
      }
    __syncthreads();
  }
#pragma unroll
  for (int mf = 0; mf < 2; mf++)
#pragma unroll
    for (int r = 0; r < 4; r++) {
      const int rowl = wm * 32 + mf * 16 + q * 4 + r;
      const int row = m0 + rowl;
      float mm = 0.f, rs = 0.f;
      if constexpr (MODE == 5) {
        float ts = red[0][rowl][0] + red[0][rowl][1];
        float tq = red[1][rowl][0] + red[1][rowl][1];
        mm = ts * (1.f / 128.f);
        float var = tq * (1.f / 128.f) - mm * mm;
        rs = rsqrtf(var + 1e-5f);
      }
#pragma unroll
      for (int nf = 0; nf < 4; nf++) {
        const int col = n0 + nf * 16 + l15;
        float v = acc[mf][nf][r];
        emb[(size_t)row * 128 + col] = f2bf(v);
        if constexpr (MODE == 5)
          ((ushort*)out2v)[(size_t)row * 128 + col] = f2bf((v - mm) * rs * lw[col] + lb[col]);
        else
          ((ushort*)out2v)[(size_t)row * 256 + 128 + col] = f2bf(v);
      }
    }
}

// ---------------- register chunked scan ----------------
__global__ __launch_bounds__(64) void k_scan(const float* __restrict__ UT, float* __restrict__ HST,
                                             const float* __restrict__ A_log) {
  const int b = blockIdx.x >> 4, ds = blockIdx.x & 15;
  const int tid = threadIdx.x;
  const float a = expf(-expf(A_log[ds]));   // keep libm: amplified through a^64
  const float4* ut4 = (const float4*)(UT + ((size_t)(b * 16 + ds)) * 4096 + tid * 64);
  float r[64];
#pragma unroll
  for (int j4 = 0; j4 < 16; j4++) {
    float4 v = ut4[j4];
    r[j4 * 4 + 0] = v.x; r[j4 * 4 + 1] = v.y; r[j4 * 4 + 2] = v.z; r[j4 * 4 + 3] = v.w;
  }
  float h = 0.f;
#pragma unroll
  for (int j = 0; j < 64; j++) { h = a * h + r[j]; r[j] = h; }
  float a64 = a;
#pragma unroll
  for (int qq = 0; qq < 6; qq++) a64 *= a64;
  float Ac = a64, Bc = h;
#pragma unroll
  for (int off = 1; off < 64; off <<= 1) {
    float Ap = __shfl_up(Ac, off);
    float Bp = __shfl_up(Bc, off);
    if (tid >= off) { Bc = Ac * Bp + Bc; Ac = Ac * Ap; }
  }
  float carry = __shfl_up(Bc, 1);
  if (tid == 0) carry = 0.f;
  float p = a;
#pragma unroll
  for (int j = 0; j < 64; j++) { r[j] += p * carry; p *= a; }
  float4* hb4 = (float4*)(HST + ((size_t)(b * 16 + ds)) * 4096 + tid * 64);
#pragma unroll
  for (int j4 = 0; j4 < 16; j4++) {
    float4 v; v.x = r[j4 * 4 + 0]; v.y = r[j4 * 4 + 1]; v.z = r[j4 * 4 + 2]; v.w = r[j4 * 4 + 3];
    hb4[j4] = v;
  }
}

// ---------------- y = (hs @ D) * z ----------------
__global__ __launch_bounds__(256) void k_yb(const float* __restrict__ HST, const float* __restrict__ Dm_,
                                            const ushort* __restrict__ Z, ushort* __restrict__ Y) {
  const int m = blockIdx.x * 2 + (threadIdx.x >> 7);
  const int d = threadIdx.x & 127;
  const int b = m >> 12, l = m & 4095;
  const float* hb = HST + (size_t)b * 16 * Ln + l;
  float acc = 0.f;
#pragma unroll
  for (int s = 0; s < 16; s++) acc += hb[(size_t)s * Ln] * Dm_[s * 128 + d];
  const size_t o = (size_t)m * 128 + d;
  Y[o] = f2bf(acc * bf2f(Z[o]));
}

// ---------------- LDS-staged implicit-GEMM conv (WPB waves/block) ----------------
template <int MODE, int OTH, int OTW, int CIN, int WPB>
__global__ __launch_bounds__(WPB * 64) void k_cv(
    const ushort* __restrict__ in, ushort* __restrict__ out,
    const ushort* __restrict__ wt, const float* __restrict__ bias,
    int Hi, int Wi, int CP, int CO, int CPo, int COo, int Cout,
    int nsp, int nspx, long ibs, long obs) {
  constexpr int ITH = (MODE == 1) ? (2 * OTH + 1) : (OTH + 2);
  constexpr int ITW = (MODE == 1) ? (2 * OTW + 1) : (OTW + 2);
  constexpr int NPIX = ITH * ITW;
  constexpr int SPF = OTH * OTW / 16;
  constexpr int NTAPS = (MODE == 2) ? 4 : 9;
  constexpr int NCH = CIN / 32;
  __shared__ __attribute__((aligned(16))) ushort lds[NPIX * 40];
  const int t = threadIdx.x;
  const int w = t >> 6, l = t & 63;
  const int l15 = l & 15, q = l >> 4;
  const int b = blockIdx.z;
  const int py = (MODE == 2) ? ((int)blockIdx.y >> 1) : 0;
  const int px = (MODE == 2) ? ((int)blockIdx.y & 1) : 0;
  const int cb = blockIdx.x / nsp;
  const int spt = blockIdx.x - cb * nsp;
  const int spy = spt / nspx, spx = spt - spy * nspx;
  const int n0 = cb * (16 * WPB) + w * 16;
  const int y0 = spy * OTH, x0 = spx * OTW;
  const int gy0 = (MODE == 1) ? (2 * y0 - 1) : (y0 - 1);
  const int gx0 = (MODE == 1) ? (2 * x0 - 1) : (x0 - 1);
  const ushort* ib = in + (size_t)b * ibs;
  f32x4 acc[SPF] = {};
  int abase[SPF];
#pragma unroll
  for (int af = 0; af < SPF; af++) {
    int p = af * 16 + l15;
    int ty = p / OTW, tx = p % OTW;
    int sy = (MODE == 1) ? (2 * ty) : ty;
    int sx = (MODE == 1) ? (2 * tx) : tx;
    abase[af] = (sy * ITW + sx) * 40 + q * 8;
  }
  for (int c = 0; c < NCH; c++) {
    const int k0 = c * 32;
    __syncthreads();
    for (int idx = t; idx < NPIX * 4; idx += WPB * 64) {
      int pix = idx >> 2, qq = idx & 3;
      int sy = pix / ITW, sx = pix - sy * ITW;
      int gy = gy0 + sy, gx = gx0 + sx;
      bfx8 v = {0, 0, 0, 0, 0, 0, 0, 0};
      if ((unsigned)gy < (unsigned)Hi && (unsigned)gx < (unsigned)Wi)
        v = *(const bfx8*)(ib + (size_t)(gy * Wi + gx) * CP + CO + k0 + qq * 8);
      *(bfx8*)&lds[pix * 40 + qq * 8] = v;
    }
    __syncthreads();
#pragma unroll
    for (int tap = 0; tap < NTAPS; tap++) {
      const int dy = (MODE == 2) ? (tap >> 1) : (tap / 3);
      const int dx = (MODE == 2) ? (tap & 1) : (tap - (tap / 3) * 3);
      const int tapw = (MODE == 2) ? ((3 - py - 2 * dy) * 4 + (3 - px - 2 * dx)) : tap;
      const int toff = (MODE == 2) ? (((py + dy) * ITW + (px + dx)) * 40)
                                   : ((dy * ITW + dx) * 40);
      bfx8 bv = *(const bfx8*)(wt + ((size_t)tapw * Cout + n0 + l15) * CIN + k0 + q * 8);
#pragma unroll
      for (int af = 0; af < SPF; af++) {
        bfx8 av = *(const bfx8*)&lds[abase[af] + toff];
        acc[af] = __builtin_amdgcn_mfma_f32_16x16x32_bf16(av, bv, acc[af], 0, 0, 0);
      }
    }
  }
  const float bb = bias[n0 + l15];
  ushort* ob = out + (size_t)b * obs + COo + n0 + l15;
#pragma unroll
  for (int af = 0; af < SPF; af++) {
#pragma unroll
    for (int r = 0; r < 4; r++) {
      int p = af * 16 + q * 4 + r;
      int ty = p / OTW, tx = p % OTW;
      int oy, ox, Wo;
      if (MODE == 2) { oy = (y0 + ty) * 2 + py; ox = (x0 + tx) * 2 + px; Wo = Wi * 2; }
      else if (MODE == 1) { oy = y0 + ty; ox = x0 + tx; Wo = Wi / 2; }
      else { oy = y0 + ty; ox = x0 + tx; Wo = Wi; }
      ob[(size_t)(oy * Wo + ox) * CPo] = f2bf(fmaxf(acc[af][r] + bb, 0.f));
    }
  }
}

// ---------------- final 1x1 conv 256 -> 2, wave-per-row shuffle reduce ----------------
__global__ __launch_bounds__(256) void k_final3(const ushort* __restrict__ in, const float* __restrict__ w,
                                                const float* __restrict__ bias, float* __restrict__ out) {
  int wid = (blockIdx.x << 2) + (threadIdx.x >> 6); // row 0..65535
  int lane = threadIdx.x & 63;
  const ushort* rp = in + (size_t)wid * 256 + lane * 4;
  ushort4 u = *(const ushort4*)rp;
  float f0 = bf2f(u.x), f1 = bf2f(u.y), f2 = bf2f(u.z), f3 = bf2f(u.w);
  float4 w0 = *(const float4*)(w + lane * 4);
  float4 w1 = *(const float4*)(w + 256 + lane * 4);
  float a0 = f0 * w0.x + f1 * w0.y + f2 * w0.z + f3 * w0.w;
  float a1 = f0 * w1.x + f1 * w1.y + f2 * w1.z + f3 * w1.w;
#pragma unroll
  for (int off = 32; off; off >>= 1) { a0 += __shfl_xor(a0, off); a1 += __shfl_xor(a1, off); }
  if (lane == 0) {
    int b = wid >> 12, p = wid & 4095;
    out[(size_t)b * 8192 + p] = a0 + bias[0];
    out[(size_t)b * 8192 + 4096 + p] = a1 + bias[1];
  }
}

extern "C" void kernel_launch(void* const* d_in, const int* in_sizes, int n_in,
                              void* d_out, int out_size, void* d_ws, size_t ws_size,
                              hipStream_t stream) {
  (void)in_sizes; (void)n_in; (void)out_size; (void)ws_size;
  const float* x          = (const float*)d_in[0];
  const float* emb_w      = (const float*)d_in[1];
  const float* emb_b      = (const float*)d_in[2];
  const float* pos_embed  = (const float*)d_in[3];
  const float* time_embed = (const float*)d_in[4];
  const float* blk_ln1_w  = (const float*)d_in[5];
  const float* blk_ln1_b  = (const float*)d_in[6];
  const float* blk_conv_w = (const float*)d_in[7];
  const float* blk_conv_b = (const float*)d_in[8];
  const float* blk_sln_w  = (const float*)d_in[9];
  const float* blk_sln_b  = (const float*)d_in[10];
  const float* blk_A_log  = (const float*)d_in[11];
  const float* blk_D      = (const float*)d_in[12];
  const float* blk_in_w   = (const float*)d_in[13];
  const float* blk_in_b   = (const float*)d_in[14];
  const float* blk_x_w    = (const float*)d_in[15];
  const float* blk_x_b    = (const float*)d_in[16];
  const float* blk_out_w  = (const float*)d_in[17];
  const float* blk_out_b  = (const float*)d_in[18];
  const float* blk_ln2_w  = (const float*)d_in[19];
  const float* blk_ln2_b  = (const float*)d_in[20];
  const float* blk_mlp_w1 = (const float*)d_in[21];
  const float* blk_mlp_b1 = (const float*)d_in[22];
  const float* blk_mlp_w2 = (const float*)d_in[23];
  const float* blk_mlp_b2 = (const float*)d_in[24];
  const float* down1_w    = (const float*)d_in[25];
  const float* down1_b    = (const float*)d_in[26];
  const float* down2_w    = (const float*)d_in[27];
  const float* down2_b    = (const float*)d_in[28];
  const float* bott_w     = (const float*)d_in[29];
  const float* bott_b     = (const float*)d_in[30];
  const float* up1_w      = (const float*)d_in[31];
  const float* up1_b      = (const float*)d_in[32];
  const float* up2_w      = (const float*)d_in[33];
  const float* up2_b      = (const float*)d_in[34];
  const float* final_w    = (const float*)d_in[35];
  const float* final_b    = (const float*)d_in[36];

  // workspace layout (float offsets, F = 1Mi floats):
  //  EMBh 0-4F (bf16) | XN1 8-12F | XN2 12-16F | MH/U2C 16-24F | Zu 24-28F
  //  W3+CWT 28-29.2F | Ubuf 32-33F | HST 33-34F      (no overlaps!)
  float* ws = (float*)d_ws;
  constexpr size_t F = 1u << 20;
  ushort* EMBh = (ushort*)ws;                 // bf16 residual [M,128]
  ushort* XN1 = (ushort*)(ws + 8 * F);        // ln1-out bf16 [M,128]
  ushort* XN2 = XN1 + 8 * F;                  // sln-out / y bf16 [M,128]
  ushort* MH  = (ushort*)(ws + 16 * F);       // mlp hidden bf16 [M,256] / U2C
  ushort* Zu  = (ushort*)(ws + 24 * F);       // z bf16 [M,128]
  ushort* W3  = (ushort*)(ws + 28 * F);       // preprocessed weights
  float* Ubuf = ws + 32 * F;                  // xc scratch, then U_T fp32
  float* HST  = ws + 33 * F;                  // hs^T fp32

  // W3 offsets (ushorts)
  ushort* Wi  = W3;                 // 2*256*128
  ushort* Wo  = W3 + 65536;         // 2*128*128
  ushort* Wm1 = W3 + 98304;         // 2*256*128
  ushort* Wm2 = W3 + 163840;        // 2*128*256
  ushort* Wx  = W3 + 229376;        // 2*16*128
  ushort* Wd1 = W3 + 233472;        // 9*128*128
  ushort* Wd2 = W3 + 380928;        // 9*256*128
  ushort* Wb9 = W3 + 675840;        // 9*256*256
  ushort* Wu1 = W3 + 1265664;       // 16*128*256
  ushort* Wu2 = W3 + 1789952;       // 16*128*256
  float*  CWT = (float*)(W3 + 2314240); // 2*4*128 fp32

  k_prep<<<9044, 256, 0, stream>>>(blk_in_w, blk_out_w, blk_mlp_w1, blk_mlp_w2, blk_x_w,
                                   blk_conv_w, down1_w, down2_w, bott_w, up1_w, up2_w, W3, CWT);
  k_combine<<<256, 256, 0, stream>>>(x, Ubuf);
  k_embedln<<<8192, 256, 0, stream>>>(Ubuf, emb_w, emb_b, pos_embed, time_embed,
                                      blk_ln1_w, blk_ln1_b, EMBh, XN1);

  ushort* U2C = MH; // [B,64,64,256] channels-last (written by mlp2 MODE4 + up2)
  for (int i = 0; i < 2; i++) {
    k_fuse1<<<4096, 256, 0, stream>>>(XN1, EMBh, XN2, CWT + i * 512, blk_conv_b + i * Dn,
                                      blk_sln_w + i * Dn, blk_sln_b + i * Dn);
    k_gemm_xz<<<dim3(512, 2), 256, 0, stream>>>(XN2, Wi + i * 32768, blk_in_b + i * 256,
                                                Zu, Wx + i * 2048, blk_x_b + i * DSn, Ubuf);
    k_scan<<<256, 64, 0, stream>>>(Ubuf, HST, blk_A_log + i * DSn);
    k_yb<<<32768, 256, 0, stream>>>(HST, blk_D + i * DSn * Dn, Zu, XN2);
    k_gemm_om<<<1024, 256, 0, stream>>>(XN2, Wo + i * 16384, blk_out_b + i * Dn,
                                        EMBh, blk_ln2_w + i * Dn, blk_ln2_b + i * Dn,
                                        Wm1 + i * 32768, blk_mlp_b1 + i * 256, MH);
    if (i == 0)
      k_mgemm<5, 256><<<1024, 256, 0, stream>>>(MH, Wm2 + i * 32768, blk_mlp_b2 + i * Dn,
                                                XN1, EMBh, blk_ln1_w + Dn, blk_ln1_b + Dn);
    else
      k_mgemm<4, 256><<<1024, 256, 0, stream>>>(MH, Wm2 + i * 32768, blk_mlp_b2 + i * Dn,
                                                U2C, EMBh, nullptr, nullptr);
  }

  // ---- UNet head, channels-last bf16 ----
  ushort* U1C = XN1;              // [B,32,32,256] (dead XN1 region)
  ushort* X2b = XN1 + 8388608;    // [B,16,16,256] (dead XN2 region)
  ushort* X3b = X2b + 1048576;    // [B,16,16,256]

  k_cv<1, 8, 8, 128, 4><<<dim3(2 * 16, 1, 16), 256, 0, stream>>>(
      U2C, U1C, Wd1, down1_b, 64, 64, 256, 128, 256, 128, 128,
      16, 4, 64L * 64 * 256, 32L * 32 * 256);
  k_cv<1, 8, 8, 128, 2><<<dim3(8 * 4, 1, 16), 128, 0, stream>>>(
      U1C, X2b, Wd2, down2_b, 32, 32, 256, 128, 256, 0, 256,
      4, 2, 32L * 32 * 256, 16L * 16 * 256);
  k_cv<0, 8, 8, 256, 2><<<dim3(8 * 4, 1, 16), 128, 0, stream>>>(
      X2b, X3b, Wb9, bott_b, 16, 16, 256, 0, 256, 0, 256,
      4, 2, 16L * 16 * 256, 16L * 16 * 256);
  k_cv<2, 8, 16, 256, 2><<<dim3(4 * 2, 4, 16), 128, 0, stream>>>(
      X3b, U1C, Wu1, up1_b, 16, 16, 256, 0, 256, 0, 128,
      2, 1, 16L * 16 * 256, 32L * 32 * 256);
  k_cv<2, 16, 16, 256, 4><<<dim3(2 * 4, 4, 16), 256, 0, stream>>>(
      U1C, U2C, Wu2, up2_b, 32, 32, 256, 0, 256, 0, 128,
      4, 2, 32L * 32 * 256, 64L * 64 * 256);

  k_final3<<<16384, 256, 0, stream>>>(U2C, final_w, final_b, (float*)d_out);
}